// Round 5
// baseline (126.481 us; speedup 1.0000x reference)
//
#include <hip/hip_runtime.h>
#include <hip/hip_bf16.h>

typedef __attribute__((ext_vector_type(8))) short short8;
typedef __attribute__((ext_vector_type(4))) float f32x4;
typedef unsigned short u16;
typedef unsigned int u32;

// B=512, M=40, H=128, D=64, C=128. K' = hh*320 + m*8 + hl (h = hh*8+hl),
// 160 K-tiles of 32; tile t: hh = t/10, m = 4*(t%10)+quad, hl = j (0..7).
#define NB 512
#define NM 40
#define NH 128
#define ND 64
#define NC 128
#define KTOT 5120
#define XKP 132   // xkT (f32) row pad: stride 528 B, 16B-aligned, 2-way banks
#define X0P 68    // x0s row pad: stride 272 B, 16B-aligned

__device__ __forceinline__ u16 f2bf_rne(float f) {
    u32 u = __float_as_uint(f);
    u32 r = u + 0x7FFFu + ((u >> 16) & 1u);
    return (u16)(r >> 16);
}

// pack two f32 into a bf16 pair (truncate) -- 1 v_perm
__device__ __forceinline__ u32 pack2(float f0, float f1) {
    return __builtin_amdgcn_perm(__float_as_uint(f1), __float_as_uint(f0),
                                 0x07060302u);
}

// b_frag = bf16(s * xv[0..7]); vector mul -> v_pk_mul_f32 (4 muls + 4 perms)
__device__ __forceinline__ short8 bmul(float s, f32x4 a, f32x4 b) {
    union { short8 s8; u32 u4[4]; } r;
    f32x4 ma = a * s, mb = b * s;
    r.u4[0] = pack2(ma[0], ma[1]);
    r.u4[1] = pack2(ma[2], ma[3]);
    r.u4[2] = pack2(mb[0], mb[1]);
    r.u4[3] = pack2(mb[2], mb[3]);
    return r.s8;
}

// pre-kernel: W fp32 [C][h*40+m] -> bf16 W3 [t][q][c][8], k'=t*32+q*8+j;
// n8 = t*4+q: m = n8%40, hh = n8/40, h = hh*8+j. One block per channel.
__global__ void w3_kernel(const float* __restrict__ W, u16* __restrict__ W3) {
    __shared__ u16 kbuf[KTOT];
    const int c = blockIdx.x;
    const float* src = W + (size_t)c * KTOT;
    for (int k = threadIdx.x; k < KTOT; k += 256)
        kbuf[k] = f2bf_rne(src[k]);
    __syncthreads();
    for (int n8 = threadIdx.x; n8 < 640; n8 += 256) {
        int m = n8 % 40, hh = n8 / 40;
        union { short8 s8; u16 e[8]; } v;
#pragma unroll
        for (int j = 0; j < 8; ++j)
            v.e[j] = kbuf[hh * 320 + j * 40 + m];
        int t = n8 >> 2, q = n8 & 3;
        *(short8*)(W3 + (size_t)t * 4096 + q * 1024 + c * 8) = v.s8;
    }
}

// main: 1 block/batch, 512 thr = 8 waves: kh (K-half) x rh (row-half) x
// ch (col-half). Wave tile 64 rows x 32 cols, 8 MFMA/iter, 80 iters.
// A straight from L2 into registers (1-tile prefetch, no K-loop barriers);
// B built in regs from f32 xkT in LDS (reload per 10 iters) + 2 b32 x0/iter.
__global__ void __launch_bounds__(512, 4) cin_main(
    const float* __restrict__ x0g, const float* __restrict__ xkg,
    const float* __restrict__ biasg, const u16* __restrict__ W3,
    float* __restrict__ out)
{
    __shared__ __align__(16) char smem[45184];
    float* xkT    = (float*)smem;              // [64][132] f32 = 33792 B
    float* x0s    = (float*)(smem + 33792);    // [40][68]  f32 = 10880 B
    float* bias_s = (float*)(smem + 44672);    // 512 B
    float* red    = (float*)smem;              // epilogue [128][66] = 33792 B

    const int tid = threadIdx.x;
    const int b = blockIdx.x;
    const int w = tid >> 6, L = tid & 63;
    const int q = L >> 4, l16 = L & 15;
    const int kh = (w >> 2) & 1;   // K-half: tiles [kh*80, kh*80+80)
    const int rh = (w >> 1) & 1;   // row half
    const int ch = w & 1;          // col half
    const int col0 = ch * 32 + l16;

    // A-fragment base: W3[t][q][c][8], c = rh*64 + mt*16 + l16
    const u16* Ap = W3 + q * 1024 + (size_t)(rh * 64 + l16) * 8;
    auto loadA = [&](int t, short8* a) {
#pragma unroll
        for (int mt = 0; mt < 4; ++mt)
            a[mt] = *(const short8*)(Ap + (size_t)t * 4096 + mt * 128);
    };

    short8 aC[4], aN[4];
    loadA(kh * 80, aC);            // issue before prologue: L2 latency hidden

    // ---- prologue: transpose xk -> f32 xkT, x0 -> LDS, bias
    {
        const float* xp = xkg + (size_t)b * (NH * ND);
        for (int i = tid; i < 2048; i += 512) {        // float4 per (h, d4)
            int h = i >> 4, d4 = (i & 15) << 2;
            float4 v = *(const float4*)(xp + h * ND + d4);
            xkT[(d4 + 0) * XKP + h] = v.x;
            xkT[(d4 + 1) * XKP + h] = v.y;
            xkT[(d4 + 2) * XKP + h] = v.z;
            xkT[(d4 + 3) * XKP + h] = v.w;
        }
        const float* x0p = x0g + (size_t)b * (NM * ND);
        for (int i = tid; i < 640; i += 512) {
            int m = i >> 4, d4 = (i & 15) << 2;
            *(f32x4*)(x0s + m * X0P + d4) = *(const f32x4*)(x0p + m * ND + d4);
        }
        if (tid < NC) bias_s[tid] = biasg[tid];
    }
    __syncthreads();

    f32x4 acc[4][2] = {};   // [mt rows][n cols]
    f32x4 xv[2][2];         // f32 xk frags: [n][lo/hi], 10-iter lifetime

    for (int tp = 0; tp < 8; ++tp) {
        const int hh = kh * 8 + tp;
#pragma unroll
        for (int n = 0; n < 2; ++n) {
            const float* p = &xkT[(n * 16 + col0) * XKP + hh * 8];
            xv[n][0] = *(const f32x4*)p;
            xv[n][1] = *(const f32x4*)(p + 4);
        }
#pragma unroll 2
        for (int ti = 0; ti < 10; ++ti) {
            const int tt = tp * 10 + ti;
            const int tn = (tt + 1 < 80) ? (kh * 80 + tt + 1) : kh * 80;
            loadA(tn, aN);                     // register prefetch, no LDS
            const float* px0 = x0s + (4 * ti + q) * X0P + col0;
            short8 bf0 = bmul(px0[0],  xv[0][0], xv[0][1]);
            short8 bf1 = bmul(px0[16], xv[1][0], xv[1][1]);
#pragma unroll
            for (int mt = 0; mt < 4; ++mt) {
                acc[mt][0] = __builtin_amdgcn_mfma_f32_16x16x32_bf16(aC[mt], bf0, acc[mt][0], 0, 0, 0);
                acc[mt][1] = __builtin_amdgcn_mfma_f32_16x16x32_bf16(aC[mt], bf1, acc[mt][1], 0, 0, 0);
            }
#pragma unroll
            for (int mt = 0; mt < 4; ++mt) aC[mt] = aN[mt];
        }
    }

    // ---- epilogue: 2-way K reduce via LDS; C/D layout col=l16, row=q*4+reg
    __syncthreads();
    if (kh == 1) {
#pragma unroll
        for (int mt = 0; mt < 4; ++mt)
#pragma unroll
            for (int rr = 0; rr < 4; ++rr) {
                int row = rh * 64 + mt * 16 + q * 4 + rr;
                float* p = red + row * 66 + col0;
                p[0]  = acc[mt][0][rr];
                p[16] = acc[mt][1][rr];
            }
    }
    __syncthreads();
    if (kh == 0) {
        float* op = out + (size_t)b * (NC * ND);
#pragma unroll
        for (int mt = 0; mt < 4; ++mt)
#pragma unroll
            for (int rr = 0; rr < 4; ++rr) {
                int row = rh * 64 + mt * 16 + q * 4 + rr;
                const float* p = red + row * 66 + col0;
                float bv = bias_s[row];
                op[row * ND + col0]      = acc[mt][0][rr] + p[0]  + bv;
                op[row * ND + 16 + col0] = acc[mt][1][rr] + p[16] + bv;
            }
    }
}

extern "C" void kernel_launch(void* const* d_in, const int* in_sizes, int n_in,
                              void* d_out, int out_size, void* d_ws, size_t ws_size,
                              hipStream_t stream) {
    const float* x0 = (const float*)d_in[0];
    const float* xk = (const float*)d_in[1];
    const float* W  = (const float*)d_in[2];
    const float* bi = (const float*)d_in[3];
    float* out = (float*)d_out;

    u16* W3 = (u16*)d_ws;                      // 655360 shorts = 1.31 MB

    w3_kernel<<<NC, 256, 0, stream>>>(W, W3);
    cin_main<<<NB, 512, 0, stream>>>(x0, xk, bi, W3, out);
}

// Round 6
// 123.510 us; speedup vs baseline: 1.0241x; 1.0241x over previous
//
#include <hip/hip_runtime.h>
#include <hip/hip_bf16.h>

typedef __attribute__((ext_vector_type(8))) short short8;
typedef __attribute__((ext_vector_type(4))) float f32x4;
typedef unsigned short u16;
typedef unsigned int u32;

// B=512, M=40, H=128, D=64, C=128. K' = hh*320 + m*8 + hl (h = hh*8+hl),
// 160 K-tiles of 32; tile t: hh = t/10, m = 4*(t%10)+quad, hl = j (0..7).
#define NB 512
#define NM 40
#define NH 128
#define ND 64
#define NC 128
#define KTOT 5120

__device__ __forceinline__ u16 f2bf_rne(float f) {
    u32 u = __float_as_uint(f);
    u32 r = u + 0x7FFFu + ((u >> 16) & 1u);
    return (u16)(r >> 16);
}
__device__ __forceinline__ float bf2f(short s) {
    return __uint_as_float(((u32)(u16)s) << 16);
}

// b_frag[j] = bf16(s * bf16(xv[j]))  -- v_perm packs 2 per inst
__device__ __forceinline__ short8 bmul(float s, short8 xv) {
    union { short8 s8; u32 u4[4]; } r;
#pragma unroll
    for (int j = 0; j < 4; ++j) {
        float f0 = s * bf2f(xv[2 * j]);
        float f1 = s * bf2f(xv[2 * j + 1]);
        r.u4[j] = __builtin_amdgcn_perm(__float_as_uint(f1), __float_as_uint(f0),
                                        0x07060302u);
    }
    return r.s8;
}

// pre-kernel: W fp32 [C][h*40+m] -> bf16 W3 [t][q][c][8], k'=t*32+q*8+j;
// n8 = t*4+q: m = n8%40, hh = n8/40, h = hh*8+j. One block per channel.
__global__ void w3_kernel(const float* __restrict__ W, u16* __restrict__ W3) {
    __shared__ u16 kbuf[KTOT];
    const int c = blockIdx.x;
    const float* src = W + (size_t)c * KTOT;
    for (int k = threadIdx.x; k < KTOT; k += 256)
        kbuf[k] = f2bf_rne(src[k]);
    __syncthreads();
    for (int n8 = threadIdx.x; n8 < 640; n8 += 256) {
        int m = n8 % 40, hh = n8 / 40;
        union { short8 s8; u16 e[8]; } v;
#pragma unroll
        for (int j = 0; j < 8; ++j)
            v.e[j] = kbuf[hh * 320 + j * 40 + m];
        int t = n8 >> 2, q = n8 & 3;
        *(short8*)(W3 + (size_t)t * 4096 + q * 1024 + c * 8) = v.s8;
    }
}

// main: 1 block per 2 batches (grid 256 = 1 block/CU), 512 thr = 8 waves:
// kh (K-quarter, 40 tiles each) x rh (row half). Wave tile 64 rows x 128
// cols (2 batches x D=64): 32 MFMA per iter from ONE 4KB A-load -> L1 port
// pressure halved vs 64-col tiles. A straight from L2 into registers
// (1-tile prefetch, no K-loop barriers). 4-way K-reduce epilogue in LDS.
__global__ void __launch_bounds__(512, 2) cin_main(
    const float* __restrict__ x0g, const float* __restrict__ xkg,
    const float* __restrict__ biasg, const u16* __restrict__ W3,
    float* __restrict__ out)
{
    // [0,34816) xkT bf16 [2][64][136] | [34816,56576) x0s f32 [2][40][68]
    // epilogue overlay: bufA f32 [2][64][132] at 0, bufB at 67584
    // bias at 135168 (outside both overlays)
    __shared__ __align__(16) char smem[135680];
    short* xkT    = (short*)smem;
    float* x0s    = (float*)(smem + 34816);
    float* bufA   = (float*)smem;
    float* bufB   = (float*)(smem + 67584);
    float* bias_s = (float*)(smem + 135168);

    const int tid = threadIdx.x;
    const int w = tid >> 6, L = tid & 63;
    const int q = L >> 4, l16 = L & 15;
    const int kh = w >> 1;          // K-quarter: tiles [kh*40, kh*40+40)
    const int rh = w & 1;           // row half
    const size_t b0 = 2 * (size_t)blockIdx.x;

    // A-fragment base: W3[t][q][c][8], c = rh*64 + mt*16 + l16
    const u16* Ap = W3 + q * 1024 + (size_t)(rh * 64 + l16) * 8;
    auto loadA = [&](int t, short8* a) {
#pragma unroll
        for (int mt = 0; mt < 4; ++mt)
            a[mt] = *(const short8*)(Ap + (size_t)t * 4096 + mt * 128);
    };

    short8 aC[4], aN[4];
    const int t0 = kh * 40;
    loadA(t0, aC);                  // issue before prologue: L2 latency hidden

    // ---- prologue: 2 batches of xk -> bf16 xkT (transposed), x0 -> LDS
    {
        for (int i = tid; i < 4096; i += 512) {       // (bn, h, d4)
            int bn = i >> 11, rem = i & 2047;
            int h = rem >> 4, d4 = (rem & 15) << 2;
            float4 v = *(const float4*)(xkg + (b0 + bn) * (NH * ND) + h * ND + d4);
            short* xT = xkT + bn * 8704;
            xT[(d4 + 0) * 136 + h] = (short)f2bf_rne(v.x);
            xT[(d4 + 1) * 136 + h] = (short)f2bf_rne(v.y);
            xT[(d4 + 2) * 136 + h] = (short)f2bf_rne(v.z);
            xT[(d4 + 3) * 136 + h] = (short)f2bf_rne(v.w);
        }
        for (int i = tid; i < 1280; i += 512) {       // (bn, m, d4)
            int bn = i / 640, rem = i % 640;
            int m = rem >> 4, d4 = (rem & 15) << 2;
            *(f32x4*)(x0s + bn * 2720 + m * 68 + d4) =
                *(const f32x4*)(x0g + (b0 + bn) * (NM * ND) + m * ND + d4);
        }
        if (tid < NC) bias_s[tid] = biasg[tid];
    }
    __syncthreads();

    f32x4 acc[4][8] = {};   // [mt rows][n cols]; n<4 batch0, n>=4 batch1
    short8 xv[8];           // xk frags, 10-iter lifetime

    for (int tp = 0; tp < 4; ++tp) {
        const int hh = kh * 4 + tp;
#pragma unroll
        for (int n = 0; n < 8; ++n) {
            const short* xT = xkT + (n >> 2) * 8704;
            xv[n] = *(const short8*)&xT[((n & 3) * 16 + l16) * 136 + hh * 8];
        }
#pragma unroll 2
        for (int ti = 0; ti < 10; ++ti) {
            const int tt = tp * 10 + ti;
            const int tn = (tt + 1 < 40) ? (t0 + tt + 1) : t0;
            loadA(tn, aN);                 // register prefetch, no LDS
            const float* p0 = x0s + (4 * ti + q) * 68 + l16;
            const float* p1 = p0 + 2720;
#pragma unroll
            for (int n = 0; n < 8; ++n) {
                float s = (n < 4) ? p0[(n & 3) * 16] : p1[(n & 3) * 16];
                short8 bf = bmul(s, xv[n]);
                acc[0][n] = __builtin_amdgcn_mfma_f32_16x16x32_bf16(aC[0], bf, acc[0][n], 0, 0, 0);
                acc[1][n] = __builtin_amdgcn_mfma_f32_16x16x32_bf16(aC[1], bf, acc[1][n], 0, 0, 0);
                acc[2][n] = __builtin_amdgcn_mfma_f32_16x16x32_bf16(aC[2], bf, acc[2][n], 0, 0, 0);
                acc[3][n] = __builtin_amdgcn_mfma_f32_16x16x32_bf16(aC[3], bf, acc[3][n], 0, 0, 0);
            }
#pragma unroll
            for (int mt = 0; mt < 4; ++mt) aC[mt] = aN[mt];
        }
    }

    // ---- epilogue: 4-way K-reduce. Buffers col-major [bn][d][132]+c so the
    // 4 acc regs (consecutive rows c) form one f32x4 -> ds_*_b128.
    const int cbase = rh * 64 + q * 4;
    auto bufp = [&](float* buf, int mt, int n) -> float* {
        int d = (n & 3) * 16 + l16;
        return buf + (n >> 2) * 8448 + d * 132 + cbase + mt * 16;
    };
    __syncthreads();
    if (kh & 1) {                         // kh = 1 -> bufA, kh = 3 -> bufB
        float* buf = (kh == 1) ? bufA : bufB;
#pragma unroll
        for (int mt = 0; mt < 4; ++mt)
#pragma unroll
            for (int n = 0; n < 8; ++n)
                *(f32x4*)bufp(buf, mt, n) = acc[mt][n];
    }
    __syncthreads();
    if (!(kh & 1)) {                      // kh = 0 += bufA, kh = 2 += bufB
        float* buf = (kh == 0) ? bufA : bufB;
#pragma unroll
        for (int mt = 0; mt < 4; ++mt)
#pragma unroll
            for (int n = 0; n < 8; ++n)
                acc[mt][n] += *(const f32x4*)bufp(buf, mt, n);
    }
    __syncthreads();
    if (kh == 2) {
#pragma unroll
        for (int mt = 0; mt < 4; ++mt)
#pragma unroll
            for (int n = 0; n < 8; ++n)
                *(f32x4*)bufp(bufA, mt, n) = acc[mt][n];
    }
    __syncthreads();
    if (kh == 0) {
#pragma unroll
        for (int mt = 0; mt < 4; ++mt)
#pragma unroll
            for (int n = 0; n < 8; ++n) {
                acc[mt][n] += *(const f32x4*)bufp(bufA, mt, n);
                int bn = n >> 2, d = (n & 3) * 16 + l16;
                float* op = out + (b0 + bn) * (NC * ND);
#pragma unroll
                for (int rr = 0; rr < 4; ++rr) {
                    int c = cbase + mt * 16 + rr;
                    op[c * ND + d] = acc[mt][n][rr] + bias_s[c];
                }
            }
    }
}

extern "C" void kernel_launch(void* const* d_in, const int* in_sizes, int n_in,
                              void* d_out, int out_size, void* d_ws, size_t ws_size,
                              hipStream_t stream) {
    const float* x0 = (const float*)d_in[0];
    const float* xk = (const float*)d_in[1];
    const float* W  = (const float*)d_in[2];
    const float* bi = (const float*)d_in[3];
    float* out = (float*)d_out;

    u16* W3 = (u16*)d_ws;                      // 655360 shorts = 1.31 MB

    w3_kernel<<<NC, 256, 0, stream>>>(W, W3);
    cin_main<<<NB / 2, 512, 0, stream>>>(x0, xk, bi, W3, out);
}

// Round 7
// 117.344 us; speedup vs baseline: 1.0779x; 1.0525x over previous
//
#include <hip/hip_runtime.h>
#include <hip/hip_bf16.h>

typedef __attribute__((ext_vector_type(8))) short short8;
typedef __attribute__((ext_vector_type(4))) float f32x4;
typedef unsigned short u16;
typedef unsigned int u32;

// B=512, M=40, H=128, D=64, C=128.
// Factored algebra: out[c,d] = sum_m x0[m,d] * T_m[c,d],
//   T_m[c,d] = sum_h W[c,h,m] * xk[h,d]   (pure bf16 GEMM, K=H=128)
// Telescoped: T never zeroed; out += (s_m - s_{m+1}) * T_cum.
#define NB 512
#define NM 40
#define NH 128
#define ND 64
#define NC 128
#define KTOT 5120

__device__ __forceinline__ u16 f2bf_rne(float f) {
    u32 u = __float_as_uint(f);
    u32 r = u + 0x7FFFu + ((u >> 16) & 1u);
    return (u16)(r >> 16);
}

// pre-kernel: W fp32 [C][h*40+m] -> bf16 W3 [m][t][q][c][8], h = t*32+q*8+j.
// One block per channel c: coalesced read, LDS, 16B writes.
__global__ void w3_kernel(const float* __restrict__ W, u16* __restrict__ W3) {
    __shared__ u16 kbuf[KTOT];
    const int c = blockIdx.x;
    const float* src = W + (size_t)c * KTOT;
    for (int k = threadIdx.x; k < KTOT; k += 256)
        kbuf[k] = f2bf_rne(src[k]);
    __syncthreads();
    for (int n = threadIdx.x; n < 640; n += 256) {   // n = m*16 + t*4 + q
        int m = n >> 4, t = (n >> 2) & 3, q = n & 3;
        union { short8 s8; u16 e[8]; } v;
#pragma unroll
        for (int j = 0; j < 8; ++j)
            v.e[j] = kbuf[(t * 32 + q * 8 + j) * NM + m];
        *(short8*)(W3 + ((size_t)n * 128 + c) * 8) = v.s8;
    }
}

// main: grid 256 (2 batches/block), 512 thr = 8 waves = bh x rh x mh.
// Wave: 64 rows (rh) x 64 cols (batch bh), m in [mh*20, mh*20+20).
// Per m: 4 K-tiles of pure MFMA (A reg-prefetched from L2 1 t-tile ahead,
// B = xk frags from LDS, m-invariant); then out += (s_m - s_{m+1}) * T.
__global__ void __launch_bounds__(512, 2) cin_main(
    const float* __restrict__ x0g, const float* __restrict__ xkg,
    const float* __restrict__ biasg, const u16* __restrict__ W3,
    float* __restrict__ out)
{
    // [0,34816) xkT bf16 [2][64][136] | [34816,56576) x0s f32 [2][40][68]
    // epilogue overlay: red f32 [4][64][68] = 69632 B | bias at 69632
    __shared__ __align__(16) char smem[70144];
    short* xkT    = (short*)smem;
    float* x0s    = (float*)(smem + 34816);
    float* red    = (float*)smem;
    float* bias_s = (float*)(smem + 69632);

    const int tid = threadIdx.x;
    const int w = tid >> 6, L = tid & 63;
    const int q = L >> 4, l16 = L & 15;
    const int bh = (w >> 2) & 1;    // batch within block
    const int rh = (w >> 1) & 1;    // row half (c)
    const int mh = w & 1;           // m half: [mh*20, mh*20+20)
    const size_t b0 = 2 * (size_t)blockIdx.x;

    // A frag (m,t,mt): shorts index m*16384 + t*4096 + q*1024 + c*8,
    // c = rh*64 + mt*16 + l16
    const u16* Ap = W3 + q * 1024 + (size_t)(rh * 64 + l16) * 8;
    const int m0 = mh * 20;

    short8 aC[4], aN[4], bC[4], bN[4];
    // first A prefetch (W3 from pre-kernel, global) before prologue
#pragma unroll
    for (int mt = 0; mt < 4; ++mt)
        aN[mt] = *(const short8*)(Ap + (size_t)m0 * 16384 + mt * 128);

    // ---- prologue: 2 batches xk -> bf16 xkT (transposed), x0 -> LDS, bias
    {
        for (int i = tid; i < 4096; i += 512) {       // (bn, h, d4)
            int bn = i >> 11, rem = i & 2047;
            int h = rem >> 4, d4 = (rem & 15) << 2;
            float4 v = *(const float4*)(xkg + (b0 + bn) * (NH * ND) + h * ND + d4);
            short* xT = xkT + bn * 8704;
            xT[(d4 + 0) * 136 + h] = (short)f2bf_rne(v.x);
            xT[(d4 + 1) * 136 + h] = (short)f2bf_rne(v.y);
            xT[(d4 + 2) * 136 + h] = (short)f2bf_rne(v.z);
            xT[(d4 + 3) * 136 + h] = (short)f2bf_rne(v.w);
        }
        for (int i = tid; i < 1280; i += 512) {       // (bn, m, d4)
            int bn = i / 640, rem = i % 640;
            int m = rem >> 4, d4 = (rem & 15) << 2;
            *(f32x4*)(x0s + bn * 2720 + m * 68 + d4) =
                *(const f32x4*)(x0g + (b0 + bn) * (NM * ND) + m * ND + d4);
        }
        if (tid < NC) bias_s[tid] = biasg[tid];
    }
    __syncthreads();

    const short* xT = xkT + bh * 8704;
    const float* x0p = x0s + bh * 2720;      // [40][68]
    // B frag (t,n): xT[(n*16+l16)*136 + t*32 + q*8]
    const short* Bp = xT + (size_t)l16 * 136 + q * 8;
#pragma unroll
    for (int n = 0; n < 4; ++n)              // t = 0
        bN[n] = *(const short8*)(Bp + n * (16 * 136));

    float s[4], sn[4];
#pragma unroll
    for (int n = 0; n < 4; ++n)
        s[n] = x0p[m0 * 68 + n * 16 + l16];

    f32x4 T[4][4] = {};      // cumulative GEMM acc
    f32x4 o[4][4] = {};      // scaled output acc

    for (int mi = 0; mi < 20; ++mi) {
        const int m = m0 + mi;
        const int mnext = (mi < 19) ? m + 1 : m;   // clamped prefetch
#pragma unroll
        for (int t = 0; t < 4; ++t) {
#pragma unroll
            for (int i2 = 0; i2 < 4; ++i2) { aC[i2] = aN[i2]; bC[i2] = bN[i2]; }
            const int tn = (t + 1) & 3;
            const size_t mA = (t < 3) ? (size_t)m : (size_t)mnext;
#pragma unroll
            for (int mt = 0; mt < 4; ++mt)
                aN[mt] = *(const short8*)(Ap + mA * 16384 + tn * 4096 + mt * 128);
#pragma unroll
            for (int n = 0; n < 4; ++n)
                bN[n] = *(const short8*)(Bp + n * (16 * 136) + tn * 32);
            if (t == 0) {
#pragma unroll
                for (int n = 0; n < 4; ++n)
                    sn[n] = (mi < 19) ? x0p[(m + 1) * 68 + n * 16 + l16] : 0.f;
            }
#pragma unroll
            for (int n = 0; n < 4; ++n) {
                T[0][n] = __builtin_amdgcn_mfma_f32_16x16x32_bf16(aC[0], bC[n], T[0][n], 0, 0, 0);
                T[1][n] = __builtin_amdgcn_mfma_f32_16x16x32_bf16(aC[1], bC[n], T[1][n], 0, 0, 0);
                T[2][n] = __builtin_amdgcn_mfma_f32_16x16x32_bf16(aC[2], bC[n], T[2][n], 0, 0, 0);
                T[3][n] = __builtin_amdgcn_mfma_f32_16x16x32_bf16(aC[3], bC[n], T[3][n], 0, 0, 0);
            }
        }
        // telescoped scale: out += (s_m - s_{m+1}) * T_cum
#pragma unroll
        for (int n = 0; n < 4; ++n) {
            const float dd = s[n] - sn[n];
#pragma unroll
            for (int mt = 0; mt < 4; ++mt)
                o[mt][n] += dd * T[mt][n];
            s[n] = sn[n];
        }
    }

    // ---- epilogue: mh-pair reduce in LDS (col-major, b128, 2-way banks)
    __syncthreads();                          // xkT/x0s dead -> overlay
    float* myred = red + (bh * 2 + rh) * 4352;   // [64 d][68 c-stride]
    if (mh == 1) {
#pragma unroll
        for (int mt = 0; mt < 4; ++mt)
#pragma unroll
            for (int n = 0; n < 4; ++n) {
                int d = n * 16 + l16;
                *(f32x4*)(myred + d * 68 + mt * 16 + q * 4) = o[mt][n];
            }
    }
    __syncthreads();
    if (mh == 0) {
        float* op = out + (b0 + bh) * (NC * ND);
#pragma unroll
        for (int mt = 0; mt < 4; ++mt)
#pragma unroll
            for (int n = 0; n < 4; ++n) {
                int d = n * 16 + l16;
                f32x4 r = *(const f32x4*)(myred + d * 68 + mt * 16 + q * 4);
#pragma unroll
                for (int rr = 0; rr < 4; ++rr) {
                    int c = rh * 64 + mt * 16 + q * 4 + rr;
                    op[c * ND + d] = o[mt][n][rr] + r[rr] + bias_s[c];
                }
            }
    }
}

extern "C" void kernel_launch(void* const* d_in, const int* in_sizes, int n_in,
                              void* d_out, int out_size, void* d_ws, size_t ws_size,
                              hipStream_t stream) {
    const float* x0 = (const float*)d_in[0];
    const float* xk = (const float*)d_in[1];
    const float* W  = (const float*)d_in[2];
    const float* bi = (const float*)d_in[3];
    float* out = (float*)d_out;

    u16* W3 = (u16*)d_ws;                      // 655360 shorts = 1.31 MB

    w3_kernel<<<NC, 256, 0, stream>>>(W, W3);
    cin_main<<<NB / 2, 512, 0, stream>>>(x0, xk, bi, W3, out);
}

// Round 8
// 117.125 us; speedup vs baseline: 1.0799x; 1.0019x over previous
//
#include <hip/hip_runtime.h>
#include <hip/hip_bf16.h>

typedef __attribute__((ext_vector_type(8))) short short8;
typedef __attribute__((ext_vector_type(4))) float f32x4;
typedef unsigned short u16;
typedef unsigned int u32;

// B=512, M=40, H=128, D=64, C=128.
// Factored algebra: out[c,d] = sum_m x0[m,d] * T_m[c,d],
//   T_m[c,d] = sum_h W[c,h,m] * xk[h,d]   (pure bf16 GEMM, K=H=128)
// Telescoped: T never zeroed; out += (s_m - s_{m+1}) * T_cum.
#define NB 512
#define NM 40
#define NH 128
#define ND 64
#define NC 128
#define KTOT 5120

__device__ __forceinline__ u16 f2bf_rne(float f) {
    u32 u = __float_as_uint(f);
    u32 r = u + 0x7FFFu + ((u >> 16) & 1u);
    return (u16)(r >> 16);
}

// pre-kernel: W fp32 [C][h*40+m] -> bf16 W3 [m][t][q][c][8], h = t*32+q*8+j.
__global__ void w3_kernel(const float* __restrict__ W, u16* __restrict__ W3) {
    __shared__ u16 kbuf[KTOT];
    const int c = blockIdx.x;
    const float* src = W + (size_t)c * KTOT;
    for (int k = threadIdx.x; k < KTOT; k += 256)
        kbuf[k] = f2bf_rne(src[k]);
    __syncthreads();
    for (int n = threadIdx.x; n < 640; n += 256) {   // n = m*16 + t*4 + q
        int m = n >> 4, t = (n >> 2) & 3, q = n & 3;
        union { short8 s8; u16 e[8]; } v;
#pragma unroll
        for (int j = 0; j < 8; ++j)
            v.e[j] = kbuf[(t * 32 + q * 8 + j) * NM + m];
        *(short8*)(W3 + ((size_t)n * 128 + c) * 8) = v.s8;
    }
}

// main: grid 256 (2 batches/block), 512 thr = 8 waves = bh x rh x mh.
// Wave: 64 rows (rh) x 64 cols (batch bh), m in [mh*20, mh*20+20).
// ALL 16 B-fragments (m-invariant, 64 VGPR) register-cached before the loop:
// the hot loop is 4 global A-loads + 16 MFMA only — zero DS traffic.
__global__ void __launch_bounds__(512, 2) cin_main(
    const float* __restrict__ x0g, const float* __restrict__ xkg,
    const float* __restrict__ biasg, const u16* __restrict__ W3,
    float* __restrict__ out)
{
    // [0,34816) xkT bf16 [2][64][136] | [34816,56576) x0s f32 [2][40][68]
    // epilogue overlay: red f32 [4][64][68] = 69632 B | bias at 69632
    __shared__ __align__(16) char smem[70144];
    short* xkT    = (short*)smem;
    float* x0s    = (float*)(smem + 34816);
    float* red    = (float*)smem;
    float* bias_s = (float*)(smem + 69632);

    const int tid = threadIdx.x;
    const int w = tid >> 6, L = tid & 63;
    const int q = L >> 4, l16 = L & 15;
    const int bh = (w >> 2) & 1;    // batch within block
    const int rh = (w >> 1) & 1;    // row half (c)
    const int mh = w & 1;           // m half: [mh*20, mh*20+20)
    const size_t b0 = 2 * (size_t)blockIdx.x;

    // A frag (m,t,mt): shorts index m*16384 + t*4096 + q*1024 + c*8,
    // c = rh*64 + mt*16 + l16
    const u16* Ap = W3 + q * 1024 + (size_t)(rh * 64 + l16) * 8;
    const int m0 = mh * 20;

    short8 aC[4], aN[4];
#pragma unroll
    for (int mt = 0; mt < 4; ++mt)   // first A prefetch before prologue
        aN[mt] = *(const short8*)(Ap + (size_t)m0 * 16384 + mt * 128);

    // ---- prologue: 2 batches xk -> bf16 xkT (transposed), x0 -> LDS, bias
    {
        for (int i = tid; i < 4096; i += 512) {       // (bn, h, d4)
            int bn = i >> 11, rem = i & 2047;
            int h = rem >> 4, d4 = (rem & 15) << 2;
            float4 v = *(const float4*)(xkg + (b0 + bn) * (NH * ND) + h * ND + d4);
            short* xT = xkT + bn * 8704;
            xT[(d4 + 0) * 136 + h] = (short)f2bf_rne(v.x);
            xT[(d4 + 1) * 136 + h] = (short)f2bf_rne(v.y);
            xT[(d4 + 2) * 136 + h] = (short)f2bf_rne(v.z);
            xT[(d4 + 3) * 136 + h] = (short)f2bf_rne(v.w);
        }
        for (int i = tid; i < 1280; i += 512) {       // (bn, m, d4)
            int bn = i / 640, rem = i % 640;
            int m = rem >> 4, d4 = (rem & 15) << 2;
            *(f32x4*)(x0s + bn * 2720 + m * 68 + d4) =
                *(const f32x4*)(x0g + (b0 + bn) * (NM * ND) + m * ND + d4);
        }
        if (tid < NC) bias_s[tid] = biasg[tid];
    }
    __syncthreads();

    const short* xT = xkT + bh * 8704;
    const float* x0p = x0s + bh * 2720;      // [40][68]
    // B frag (t,n): xT[(n*16+l16)*136 + t*32 + q*8] — cache ALL 16 in regs
    const short* Bp = xT + (size_t)l16 * 136 + q * 8;
    short8 bR[4][4];
#pragma unroll
    for (int t = 0; t < 4; ++t)
#pragma unroll
        for (int n = 0; n < 4; ++n)
            bR[t][n] = *(const short8*)(Bp + n * (16 * 136) + t * 32);

    float s[4], sn[4];
#pragma unroll
    for (int n = 0; n < 4; ++n)
        s[n] = x0p[m0 * 68 + n * 16 + l16];

    f32x4 T[4][4] = {};      // cumulative GEMM acc
    f32x4 o[4][4] = {};      // scaled output acc

    for (int mi = 0; mi < 20; ++mi) {
        const int m = m0 + mi;
        const int mnext = (mi < 19) ? m + 1 : m;   // clamped prefetch
#pragma unroll
        for (int t = 0; t < 4; ++t) {
#pragma unroll
            for (int i2 = 0; i2 < 4; ++i2) aC[i2] = aN[i2];
            const int tn = (t + 1) & 3;
            const size_t mA = (t < 3) ? (size_t)m : (size_t)mnext;
#pragma unroll
            for (int mt = 0; mt < 4; ++mt)
                aN[mt] = *(const short8*)(Ap + mA * 16384 + tn * 4096 + mt * 128);
            if (t == 0) {
#pragma unroll
                for (int n = 0; n < 4; ++n)
                    sn[n] = (mi < 19) ? x0p[(m + 1) * 68 + n * 16 + l16] : 0.f;
            }
#pragma unroll
            for (int n = 0; n < 4; ++n) {
                T[0][n] = __builtin_amdgcn_mfma_f32_16x16x32_bf16(aC[0], bR[t][n], T[0][n], 0, 0, 0);
                T[1][n] = __builtin_amdgcn_mfma_f32_16x16x32_bf16(aC[1], bR[t][n], T[1][n], 0, 0, 0);
                T[2][n] = __builtin_amdgcn_mfma_f32_16x16x32_bf16(aC[2], bR[t][n], T[2][n], 0, 0, 0);
                T[3][n] = __builtin_amdgcn_mfma_f32_16x16x32_bf16(aC[3], bR[t][n], T[3][n], 0, 0, 0);
            }
        }
        // telescoped scale: out += (s_m - s_{m+1}) * T_cum
#pragma unroll
        for (int n = 0; n < 4; ++n) {
            const float dd = s[n] - sn[n];
#pragma unroll
            for (int mt = 0; mt < 4; ++mt)
                o[mt][n] += dd * T[mt][n];
            s[n] = sn[n];
        }
    }

    // ---- epilogue: mh-pair reduce in LDS (col-major, b128, 2-way banks)
    __syncthreads();                          // xkT/x0s dead -> overlay
    float* myred = red + (bh * 2 + rh) * 4352;   // [64 d][68 c-stride]
    if (mh == 1) {
#pragma unroll
        for (int mt = 0; mt < 4; ++mt)
#pragma unroll
            for (int n = 0; n < 4; ++n) {
                int d = n * 16 + l16;
                *(f32x4*)(myred + d * 68 + mt * 16 + q * 4) = o[mt][n];
            }
    }
    __syncthreads();
    if (mh == 0) {
        float* op = out + (b0 + bh) * (NC * ND);
#pragma unroll
        for (int mt = 0; mt < 4; ++mt)
#pragma unroll
            for (int n = 0; n < 4; ++n) {
                int d = n * 16 + l16;
                f32x4 r = *(const f32x4*)(myred + d * 68 + mt * 16 + q * 4);
#pragma unroll
                for (int rr = 0; rr < 4; ++rr) {
                    int c = rh * 64 + mt * 16 + q * 4 + rr;
                    op[c * ND + d] = o[mt][n][rr] + r[rr] + bias_s[c];
                }
            }
    }
}

extern "C" void kernel_launch(void* const* d_in, const int* in_sizes, int n_in,
                              void* d_out, int out_size, void* d_ws, size_t ws_size,
                              hipStream_t stream) {
    const float* x0 = (const float*)d_in[0];
    const float* xk = (const float*)d_in[1];
    const float* W  = (const float*)d_in[2];
    const float* bi = (const float*)d_in[3];
    float* out = (float*)d_out;

    u16* W3 = (u16*)d_ws;                      // 655360 shorts = 1.31 MB

    w3_kernel<<<NC, 256, 0, stream>>>(W, W3);
    cin_main<<<NB / 2, 512, 0, stream>>>(x0, xk, bi, W3, out);
}

// Round 9
// 115.931 us; speedup vs baseline: 1.0910x; 1.0103x over previous
//
#include <hip/hip_runtime.h>
#include <hip/hip_bf16.h>

typedef __attribute__((ext_vector_type(8))) short short8;
typedef __attribute__((ext_vector_type(4))) float f32x4;
typedef unsigned short u16;
typedef unsigned int u32;

// B=512, M=40, H=128, D=64, C=128.
// Factored algebra: out[c,d] = sum_m x0[m,d] * T_m[c,d],
//   T_m[c,d] = sum_h W[c,h,m] * xk[h,d]   (pure bf16 GEMM, K=H=128)
// Telescoped: T never zeroed; out += (s_m - s_{m+1}) * T_cum.
#define NB 512
#define NM 40
#define NH 128
#define ND 64
#define NC 128
#define KTOT 5120

__device__ __forceinline__ u16 f2bf_rne(float f) {
    u32 u = __float_as_uint(f);
    u32 r = u + 0x7FFFu + ((u >> 16) & 1u);
    return (u16)(r >> 16);
}

// pre-kernel: W fp32 [C][h*40+m] -> bf16 W3 [m][t][q][c][8], h = t*32+q*8+j.
__global__ void w3_kernel(const float* __restrict__ W, u16* __restrict__ W3) {
    __shared__ u16 kbuf[KTOT];
    const int c = blockIdx.x;
    const float* src = W + (size_t)c * KTOT;
    for (int k = threadIdx.x; k < KTOT; k += 256)
        kbuf[k] = f2bf_rne(src[k]);
    __syncthreads();
    for (int n = threadIdx.x; n < 640; n += 256) {   // n = m*16 + t*4 + q
        int m = n >> 4, t = (n >> 2) & 3, q = n & 3;
        union { short8 s8; u16 e[8]; } v;
#pragma unroll
        for (int j = 0; j < 8; ++j)
            v.e[j] = kbuf[(t * 32 + q * 8 + j) * NM + m];
        *(short8*)(W3 + ((size_t)n * 128 + c) * 8) = v.s8;
    }
}

// main: grid 256 (2 batches/block), 512 thr = 8 waves = bh x rh x mh.
// Wave: 64 rows (rh) x 64 cols (batch bh), m in [mh*20, mh*20+20).
// B-fragments (m-invariant) register-cached; A software-pipelined depth-2
// from L2 (circular aP[2], no copies): consuming body u waits only on loads
// issued at body u-2 -> a full body (~620 cyc) of latency slack.
__global__ void __launch_bounds__(512, 2) cin_main(
    const float* __restrict__ x0g, const float* __restrict__ xkg,
    const float* __restrict__ biasg, const u16* __restrict__ W3,
    float* __restrict__ out)
{
    // [0,34816) xkT bf16 [2][64][136] | [34816,56576) x0s f32 [2][40][68]
    // epilogue overlay: red f32 [4][64][68] = 69632 B | bias at 69632
    __shared__ __align__(16) char smem[70144];
    short* xkT    = (short*)smem;
    float* x0s    = (float*)(smem + 34816);
    float* red    = (float*)smem;
    float* bias_s = (float*)(smem + 69632);

    const int tid = threadIdx.x;
    const int w = tid >> 6, L = tid & 63;
    const int q = L >> 4, l16 = L & 15;
    const int bh = (w >> 2) & 1;    // batch within block
    const int rh = (w >> 1) & 1;    // row half (c)
    const int mh = w & 1;           // m half: [mh*20, mh*20+20)
    const size_t b0 = 2 * (size_t)blockIdx.x;

    // A frag (m,t,mt): shorts index m*16384 + t*4096 + q*1024 + c*8,
    // c = rh*64 + mt*16 + l16
    const u16* Ap = W3 + q * 1024 + (size_t)(rh * 64 + l16) * 8;
    const int m0 = mh * 20;

    short8 aP[2][4];                 // depth-2 circular A pipeline
    auto loadAstep = [&](int u, short8* dst) {
        const size_t m = (size_t)(m0 + (u >> 2));
        const int t = u & 3;
        const u16* p = Ap + m * 16384 + t * 4096;
#pragma unroll
        for (int mt = 0; mt < 4; ++mt)
            dst[mt] = *(const short8*)(p + mt * 128);
    };
    loadAstep(0, aP[0]);             // issued before prologue: latency hidden
    loadAstep(1, aP[1]);

    // ---- prologue: 2 batches xk -> bf16 xkT (transposed), x0 -> LDS, bias
    {
        for (int i = tid; i < 4096; i += 512) {       // (bn, h, d4)
            int bn = i >> 11, rem = i & 2047;
            int h = rem >> 4, d4 = (rem & 15) << 2;
            float4 v = *(const float4*)(xkg + (b0 + bn) * (NH * ND) + h * ND + d4);
            short* xT = xkT + bn * 8704;
            xT[(d4 + 0) * 136 + h] = (short)f2bf_rne(v.x);
            xT[(d4 + 1) * 136 + h] = (short)f2bf_rne(v.y);
            xT[(d4 + 2) * 136 + h] = (short)f2bf_rne(v.z);
            xT[(d4 + 3) * 136 + h] = (short)f2bf_rne(v.w);
        }
        for (int i = tid; i < 1280; i += 512) {       // (bn, m, d4)
            int bn = i / 640, rem = i % 640;
            int m = rem >> 4, d4 = (rem & 15) << 2;
            *(f32x4*)(x0s + bn * 2720 + m * 68 + d4) =
                *(const f32x4*)(x0g + (b0 + bn) * (NM * ND) + m * ND + d4);
        }
        if (tid < NC) bias_s[tid] = biasg[tid];
    }
    __syncthreads();

    const short* xT = xkT + bh * 8704;
    const float* x0p = x0s + bh * 2720;      // [40][68]
    // B frag (t,n): xT[(n*16+l16)*136 + t*32 + q*8] — cache ALL 16 in regs
    const short* Bp = xT + (size_t)l16 * 136 + q * 8;
    short8 bR[4][4];
#pragma unroll
    for (int t = 0; t < 4; ++t)
#pragma unroll
        for (int n = 0; n < 4; ++n)
            bR[t][n] = *(const short8*)(Bp + n * (16 * 136) + t * 32);

    float s[4], sn[4];
#pragma unroll
    for (int n = 0; n < 4; ++n)
        s[n] = x0p[m0 * 68 + n * 16 + l16];

    f32x4 T[4][4] = {};      // cumulative GEMM acc
    f32x4 o[4][4] = {};      // scaled output acc

#pragma unroll 4
    for (int u = 0; u < 80; ++u) {           // u = mi*4 + t
        const int t = u & 3;
        short8* aC = aP[u & 1];
        if (t == 0) {
            const int m = m0 + (u >> 2);
#pragma unroll
            for (int n = 0; n < 4; ++n)
                sn[n] = ((u >> 2) < 19) ? x0p[(m + 1) * 68 + n * 16 + l16] : 0.f;
        }
#pragma unroll
        for (int n = 0; n < 4; ++n) {
            T[0][n] = __builtin_amdgcn_mfma_f32_16x16x32_bf16(aC[0], bR[t][n], T[0][n], 0, 0, 0);
            T[1][n] = __builtin_amdgcn_mfma_f32_16x16x32_bf16(aC[1], bR[t][n], T[1][n], 0, 0, 0);
            T[2][n] = __builtin_amdgcn_mfma_f32_16x16x32_bf16(aC[2], bR[t][n], T[2][n], 0, 0, 0);
            T[3][n] = __builtin_amdgcn_mfma_f32_16x16x32_bf16(aC[3], bR[t][n], T[3][n], 0, 0, 0);
        }
        // reload consumed slot for step u+2 (clamped tail reload: harmless)
        const int up = (u + 2 < 80) ? (u + 2) : u;
        loadAstep(up, aC);
        if (t == 3) {        // telescoped scale: out += (s_m - s_{m+1}) * T
#pragma unroll
            for (int n = 0; n < 4; ++n) {
                const float dd = s[n] - sn[n];
#pragma unroll
                for (int mt = 0; mt < 4; ++mt)
                    o[mt][n] += dd * T[mt][n];
                s[n] = sn[n];
            }
        }
    }

    // ---- epilogue: mh-pair reduce in LDS (col-major, b128, 2-way banks)
    __syncthreads();                          // xkT/x0s dead -> overlay
    float* myred = red + (bh * 2 + rh) * 4352;   // [64 d][68 c-stride]
    if (mh == 1) {
#pragma unroll
        for (int mt = 0; mt < 4; ++mt)
#pragma unroll
            for (int n = 0; n < 4; ++n) {
                int d = n * 16 + l16;
                *(f32x4*)(myred + d * 68 + mt * 16 + q * 4) = o[mt][n];
            }
    }
    __syncthreads();
    if (mh == 0) {
        float* op = out + (b0 + bh) * (NC * ND);
#pragma unroll
        for (int mt = 0; mt < 4; ++mt)
#pragma unroll
            for (int n = 0; n < 4; ++n) {
                int d = n * 16 + l16;
                f32x4 r = *(const f32x4*)(myred + d * 68 + mt * 16 + q * 4);
#pragma unroll
                for (int rr = 0; rr < 4; ++rr) {
                    int c = rh * 64 + mt * 16 + q * 4 + rr;
                    op[c * ND + d] = o[mt][n][rr] + r[rr] + bias_s[c];
                }
            }
    }
}

extern "C" void kernel_launch(void* const* d_in, const int* in_sizes, int n_in,
                              void* d_out, int out_size, void* d_ws, size_t ws_size,
                              hipStream_t stream) {
    const float* x0 = (const float*)d_in[0];
    const float* xk = (const float*)d_in[1];
    const float* W  = (const float*)d_in[2];
    const float* bi = (const float*)d_in[3];
    float* out = (float*)d_out;

    u16* W3 = (u16*)d_ws;                      // 655360 shorts = 1.31 MB

    w3_kernel<<<NC, 256, 0, stream>>>(W, W3);
    cin_main<<<NB / 2, 512, 0, stream>>>(x0, xk, bi, W3, out);
}